// Round 1
// baseline (3904.040 us; speedup 1.0000x reference)
//
#include <hip/hip_runtime.h>
#include <math.h>

// NSF_CL coupling flow, fp32. N=32768, dim=256 (half=128), hid=512, K=5.
// Pipeline: repack w1 -> stage0 (cond x0, transform x1) -> stage1 (cond x1', transform x0).
// Each stage kernel fuses MLP (GEMM1+tanh in LDS, GEMM2 in registers) with the RQS spline.

#define NROWS 32768
#define DIMX  256
#define HALF  128
#define HID   512
#define NPAR  14    // 3K-1
#define BM    32    // rows per block
#define KC    8     // k-chunk for w1 staging

// ---------- spline helpers (all-register, fully unrolled) ----------

__device__ __forceinline__ float sp_f(float x) {
    // jax.nn.softplus: max(x,0) + log1p(exp(-|x|))
    return fmaxf(x, 0.f) + log1pf(expf(-fabsf(x)));
}

__device__ __forceinline__ void softmax5(const float* in, float* out) {
    float m = fmaxf(fmaxf(fmaxf(in[0], in[1]), fmaxf(in[2], in[3])), in[4]);
    float e0 = expf(in[0] - m), e1 = expf(in[1] - m), e2 = expf(in[2] - m);
    float e3 = expf(in[3] - m), e4 = expf(in[4] - m);
    float inv = 1.f / (e0 + e1 + e2 + e3 + e4);
    out[0] = e0 * inv; out[1] = e1 * inv; out[2] = e2 * inv;
    out[3] = e3 * inv; out[4] = e4 * inv;
}

// P[0..4]=W raw, P[5..9]=H raw, P[10..13]=D raw (MLP output + bias)
__device__ __forceinline__ void rqs_one(const float* P, float xa, float& yo, float& ldo) {
    float W[5], t1[5], t2[5];
    // widths: Wu = 2B*softmax(raw); widths = MIN_BW + (1-5*MIN_BW)*softmax(Wu)
    #pragma unroll
    for (int p = 0; p < 5; ++p) W[p] = P[p];
    softmax5(W, t1);
    #pragma unroll
    for (int p = 0; p < 5; ++p) t1[p] *= 6.f;
    softmax5(t1, t2);
    float cw[6], wd[5];
    cw[0] = -3.f;
    float cs = 0.f;
    #pragma unroll
    for (int p = 0; p < 5; ++p) {
        float w = 1.0e-3f + 0.995f * t2[p];
        cs += w;
        cw[p + 1] = 6.f * cs - 3.f;
    }
    cw[5] = 3.f;
    #pragma unroll
    for (int p = 0; p < 5; ++p) wd[p] = cw[p + 1] - cw[p];
    // heights
    #pragma unroll
    for (int p = 0; p < 5; ++p) W[p] = P[5 + p];
    softmax5(W, t1);
    #pragma unroll
    for (int p = 0; p < 5; ++p) t1[p] *= 6.f;
    softmax5(t1, t2);
    float ch[6], hg[5];
    ch[0] = -3.f;
    cs = 0.f;
    #pragma unroll
    for (int p = 0; p < 5; ++p) {
        float h = 1.0e-3f + 0.995f * t2[p];
        cs += h;
        ch[p + 1] = 6.f * cs - 3.f;
    }
    ch[5] = 3.f;
    #pragma unroll
    for (int p = 0; p < 5; ++p) hg[p] = ch[p + 1] - ch[p];
    // derivs: ends = MIN_D + softplus(log(exp(1-MIN_D)-1)); interior = MIN_D + sp(sp(raw))
    float dv[6];
    const float padc = logf(expf(0.999f) - 1.f);
    float dve = 1.0e-3f + sp_f(padc);
    dv[0] = dve; dv[5] = dve;
    #pragma unroll
    for (int p = 0; p < 4; ++p) dv[p + 1] = 1.0e-3f + sp_f(sp_f(P[10 + p]));

    bool inside = (xa >= -3.f) && (xa <= 3.f);
    float xc = fminf(fmaxf(xa, -3.f), 3.f);

    // bucket select: idx = max{j<=4 : xc >= cw[j]} (predicated, no runtime array idx)
    float in_cw = cw[0], in_w = wd[0], in_ch = ch[0], in_h = hg[0], dk = dv[0], dk1 = dv[1];
    #pragma unroll
    for (int jb = 1; jb < 5; ++jb) {
        bool take = (xc >= cw[jb]);
        in_cw = take ? cw[jb] : in_cw;
        in_w  = take ? wd[jb] : in_w;
        in_ch = take ? ch[jb] : in_ch;
        in_h  = take ? hg[jb] : in_h;
        dk    = take ? dv[jb] : dk;
        dk1   = take ? dv[jb + 1] : dk1;
    }
    float th = (xc - in_cw) / in_w;
    float om = 1.f - th;
    float t1m = th * om;
    float delta = in_h / in_w;
    float num = in_h * (delta * th * th + dk * t1m);
    float den = delta + (dk + dk1 - 2.f * delta) * t1m;
    float y = in_ch + num / den;
    float dnum = delta * delta * (dk1 * th * th + 2.f * delta * t1m + dk * om * om);
    float ld = logf(dnum) - 2.f * logf(den);
    yo  = inside ? y : xa;
    ldo = inside ? ld : 0.f;
}

// ---------- repack w1 [512][1792] -> [512][4][128] float4 (14 params padded to 16) ----------

__global__ void repack_w1(const float* __restrict__ w1a, const float* __restrict__ w1b,
                          float4* __restrict__ outa, float4* __restrict__ outb) {
    int f = blockIdx.x * 256 + threadIdx.x;   // 2 * 512 * 512 float4 total
    const float* src; float4* dst; int fs;
    if (f < 262144) { src = w1a; dst = outa; fs = f; }
    else            { src = w1b; dst = outb; fs = f - 262144; }
    int k = fs >> 9;
    int rem = fs & 511;
    int j = rem >> 7;     // param-quad 0..3
    int d = rem & 127;    // dim 0..127
    float v[4];
    #pragma unroll
    for (int q = 0; q < 4; ++q) {
        int p = 4 * j + q;
        v[q] = (p < NPAR) ? src[(size_t)k * 1792 + d * NPAR + p] : 0.f;
    }
    dst[fs] = make_float4(v[0], v[1], v[2], v[3]);
}

// ---------- fused stage kernel ----------

template <int STAGE>
__global__ __launch_bounds__(256, 1)
void nsf_stage(const float* __restrict__ xin,   // [N][256]
               float* __restrict__ zout,        // [N][256]
               float* __restrict__ ld_out,      // [N]
               const float* __restrict__ w0,    // [128][512]
               const float* __restrict__ b0,    // [512]
               const float4* __restrict__ w1p,  // [512][4][128] float4 (repacked)
               const float* __restrict__ b1)    // [1792]
{
    const int tid = threadIdx.x;
    const int dt = tid & 63;     // d-lane
    const int rg = tid >> 6;     // row group (wave id); each wave owns 8 rows
    const int n0 = blockIdx.x * BM;

    __shared__ float hT[BM * HID];                          // 64 KB
    __shared__ __align__(16) char smem_raw[2 * KC * 4 * 64 * 16]; // 64 KB (dbuf w1 tiles)
    typedef float4 w1buf_t[KC][4][64];
    w1buf_t* w1t = reinterpret_cast<w1buf_t*>(smem_raw);
    float* condT = reinterpret_cast<float*>(smem_raw);      // [32][128], phase-1 only alias

    const float* cond_base = (STAGE == 0) ? xin : (zout + HALF);
    const float* act_base  = (STAGE == 0) ? (xin + HALF) : xin;
    float*       y_base    = (STAGE == 0) ? (zout + HALF) : zout;

    // ---- load cond tile [32][128]
    #pragma unroll
    for (int t = 0; t < 4; ++t) {
        int f4 = t * 256 + tid;
        int row = f4 >> 5;
        int c4 = f4 & 31;
        reinterpret_cast<float4*>(condT)[f4] =
            *reinterpret_cast<const float4*>(cond_base + (size_t)(n0 + row) * DIMX + c4 * 4);
    }
    __syncthreads();

    // ---- phase 1: h = tanh(cond @ w0 + b0) -> LDS
    {
        float a1[8][8];
        #pragma unroll
        for (int i = 0; i < 8; ++i)
            #pragma unroll
            for (int j = 0; j < 8; ++j) a1[i][j] = 0.f;
        for (int k = 0; k < HALF; ++k) {
            float cv[8];
            #pragma unroll
            for (int i = 0; i < 8; ++i) cv[i] = condT[(rg * 8 + i) * HALF + k];
            #pragma unroll
            for (int jj = 0; jj < 8; ++jj) {
                float wv = w0[k * HID + dt + 64 * jj];
                #pragma unroll
                for (int i = 0; i < 8; ++i) a1[i][jj] = fmaf(cv[i], wv, a1[i][jj]);
            }
        }
        #pragma unroll
        for (int jj = 0; jj < 8; ++jj) {
            int c = dt + 64 * jj;
            float bbv = b0[c];
            #pragma unroll
            for (int i = 0; i < 8; ++i)
                hT[(rg * 8 + i) * HID + c] = tanhf(a1[i][jj] + bbv);
        }
    }
    __syncthreads();   // cond reads done; w1t staging may now overwrite the alias

    float ldacc[8];
    #pragma unroll
    for (int i = 0; i < 8; ++i) ldacc[i] = 0.f;

    // ---- phase 2: params = h @ w1 + b1, fused RQS. 64 dims per pass, 2 passes.
    for (int dl = 0; dl < 2; ++dl) {
        const int d0 = dl * 64;
        const int d = d0 + dt;
        float4 acc[8][3];
        float2 acc2[8];
        #pragma unroll
        for (int i = 0; i < 8; ++i) {
            #pragma unroll
            for (int q = 0; q < 3; ++q) acc[i][q] = make_float4(0.f, 0.f, 0.f, 0.f);
            acc2[i] = make_float2(0.f, 0.f);
        }
        float4 rstage[8];
        #pragma unroll
        for (int t = 0; t < 8; ++t) {   // prologue: chunk 0 -> regs
            int f = t * 256 + tid;
            int kk = f >> 8, rem = f & 255, j = rem >> 6, dd = rem & 63;
            rstage[t] = w1p[(size_t)kk * 512 + j * 128 + d0 + dd];
        }
        const int NCH = HID / KC;  // 64 chunks
        for (int c = 0; c < NCH; ++c) {
            const int b = c & 1;
            #pragma unroll
            for (int t = 0; t < 8; ++t) {   // regs -> LDS (waits vmcnt of prev issue)
                int f = t * 256 + tid;
                int kk = f >> 8, rem = f & 255, j = rem >> 6, dd = rem & 63;
                w1t[b][kk][j][dd] = rstage[t];
            }
            if (c + 1 < NCH) {              // issue next chunk early (T14 split)
                #pragma unroll
                for (int t = 0; t < 8; ++t) {
                    int f = t * 256 + tid;
                    int kk = f >> 8, rem = f & 255, j = rem >> 6, dd = rem & 63;
                    rstage[t] = w1p[(size_t)((c + 1) * KC + kk) * 512 + j * 128 + d0 + dd];
                }
            }
            __syncthreads();   // single barrier per chunk (dbuf makes it race-free)

            float hreg[8][8];
            #pragma unroll
            for (int i = 0; i < 8; ++i) {  // wave-uniform broadcast reads, vectorized
                const float* hp = &hT[(rg * 8 + i) * HID + c * KC];
                float4 h0 = *reinterpret_cast<const float4*>(hp);
                float4 h1 = *reinterpret_cast<const float4*>(hp + 4);
                hreg[i][0] = h0.x; hreg[i][1] = h0.y; hreg[i][2] = h0.z; hreg[i][3] = h0.w;
                hreg[i][4] = h1.x; hreg[i][5] = h1.y; hreg[i][6] = h1.z; hreg[i][7] = h1.w;
            }
            #pragma unroll
            for (int kk = 0; kk < KC; ++kk) {
                const float4 wa = w1t[b][kk][0][dt];
                const float4 wb = w1t[b][kk][1][dt];
                const float4 wc = w1t[b][kk][2][dt];
                const float2 wd2 = *reinterpret_cast<const float2*>(&w1t[b][kk][3][dt]);
                #pragma unroll
                for (int i = 0; i < 8; ++i) {
                    const float hv = hreg[i][kk];
                    acc[i][0].x = fmaf(hv, wa.x, acc[i][0].x);
                    acc[i][0].y = fmaf(hv, wa.y, acc[i][0].y);
                    acc[i][0].z = fmaf(hv, wa.z, acc[i][0].z);
                    acc[i][0].w = fmaf(hv, wa.w, acc[i][0].w);
                    acc[i][1].x = fmaf(hv, wb.x, acc[i][1].x);
                    acc[i][1].y = fmaf(hv, wb.y, acc[i][1].y);
                    acc[i][1].z = fmaf(hv, wb.z, acc[i][1].z);
                    acc[i][1].w = fmaf(hv, wb.w, acc[i][1].w);
                    acc[i][2].x = fmaf(hv, wc.x, acc[i][2].x);
                    acc[i][2].y = fmaf(hv, wc.y, acc[i][2].y);
                    acc[i][2].z = fmaf(hv, wc.z, acc[i][2].z);
                    acc[i][2].w = fmaf(hv, wc.w, acc[i][2].w);
                    acc2[i].x   = fmaf(hv, wd2.x, acc2[i].x);
                    acc2[i].y   = fmaf(hv, wd2.y, acc2[i].y);
                }
            }
        }

        // ---- bias + spline + writes
        float bb[NPAR];
        #pragma unroll
        for (int p = 0; p < NPAR; ++p) bb[p] = b1[d * NPAR + p];
        #pragma unroll
        for (int i = 0; i < 8; ++i) {
            const int n = n0 + rg * 8 + i;
            float P[NPAR];
            P[0] = acc[i][0].x + bb[0];  P[1] = acc[i][0].y + bb[1];
            P[2] = acc[i][0].z + bb[2];  P[3] = acc[i][0].w + bb[3];
            P[4] = acc[i][1].x + bb[4];  P[5] = acc[i][1].y + bb[5];
            P[6] = acc[i][1].z + bb[6];  P[7] = acc[i][1].w + bb[7];
            P[8] = acc[i][2].x + bb[8];  P[9] = acc[i][2].y + bb[9];
            P[10] = acc[i][2].z + bb[10]; P[11] = acc[i][2].w + bb[11];
            P[12] = acc2[i].x + bb[12];  P[13] = acc2[i].y + bb[13];
            float xa = act_base[(size_t)n * DIMX + d];
            float y, ldv;
            rqs_one(P, xa, y, ldv);
            y_base[(size_t)n * DIMX + d] = y;
            ldacc[i] += ldv;
        }
    }

    // ---- log-det row sums: reduce across the wave's 64 d-lanes
    #pragma unroll
    for (int i = 0; i < 8; ++i) {
        float s = ldacc[i];
        #pragma unroll
        for (int m = 1; m < 64; m <<= 1) s += __shfl_xor(s, m, 64);
        if (dt == 0) {
            const int n = n0 + rg * 8 + i;
            if (STAGE == 0) ld_out[n] = s;
            else            ld_out[n] += s;
        }
    }
}

// ---------- launch ----------

extern "C" void kernel_launch(void* const* d_in, const int* in_sizes, int n_in,
                              void* d_out, int out_size, void* d_ws, size_t ws_size,
                              hipStream_t stream) {
    const float* x     = (const float*)d_in[0];
    const float* f0_w0 = (const float*)d_in[1];
    const float* f0_b0 = (const float*)d_in[2];
    const float* f0_w1 = (const float*)d_in[3];
    const float* f0_b1 = (const float*)d_in[4];
    const float* f1_w0 = (const float*)d_in[5];
    const float* f1_b0 = (const float*)d_in[6];
    const float* f1_w1 = (const float*)d_in[7];
    const float* f1_b1 = (const float*)d_in[8];

    float* zout = (float*)d_out;
    float* ld   = zout + (size_t)NROWS * DIMX;

    float4* w1p0 = (float4*)d_ws;            // 4 MB
    float4* w1p1 = w1p0 + 512 * 512;         // 4 MB

    repack_w1<<<2048, 256, 0, stream>>>(f0_w1, f1_w1, w1p0, w1p1);
    nsf_stage<0><<<NROWS / BM, 256, 0, stream>>>(x, zout, ld, f0_w0, f0_b0, w1p0, f0_b1);
    nsf_stage<1><<<NROWS / BM, 256, 0, stream>>>(x, zout, ld, f1_w0, f1_b0, w1p1, f1_b1);
}

// Round 2
// 655.156 us; speedup vs baseline: 5.9589x; 5.9589x over previous
//
#include <hip/hip_runtime.h>
#include <math.h>

// NSF_CL coupling flow via bf16 MFMA. N=32768, dim=256 (half=128), hid=512, K=5.
// prep: repack w0/w1 -> bf16 MFMA-fragment order, pad b1 to 16.
// stage<S>: cond -> bf16 A1 frags (LDS) -> MFMA GEMM1 + tanh -> bf16 h in A2-frag
//           order (LDS) -> MFMA GEMM2 (w1 frags from L2) -> bias -> LDS transpose
//           -> RQS spline (registers) -> y + logdet.
// MFMA k-ordering chosen identically for A and B frags => result independent of
// the HW's internal k permutation. C/D layout: col=lane&15, row=(lane>>4)*4+reg.

#define NROWS 32768
#define DIMX  256
#define HALF  128
#define HID   512
#define BM    64     // rows per block

typedef __attribute__((ext_vector_type(8))) short short8;   // 8 bf16 = 4 VGPR
typedef __attribute__((ext_vector_type(4))) float f32x4;

__device__ __forceinline__ unsigned short f2bf(float x) {   // RNE f32->bf16 bits
    unsigned int u = __float_as_uint(x);
    u += 0x7fffu + ((u >> 16) & 1u);
    return (unsigned short)(u >> 16);
}

// ---------- spline (all-register, unrolled; identical numerics to r1 fp32 pass) ----------
__device__ __forceinline__ float sp_f(float x) {
    return fmaxf(x, 0.f) + log1pf(expf(-fabsf(x)));
}
__device__ __forceinline__ void softmax5(const float* in, float* out) {
    float m = fmaxf(fmaxf(fmaxf(in[0], in[1]), fmaxf(in[2], in[3])), in[4]);
    float e0 = expf(in[0] - m), e1 = expf(in[1] - m), e2 = expf(in[2] - m);
    float e3 = expf(in[3] - m), e4 = expf(in[4] - m);
    float inv = 1.f / (e0 + e1 + e2 + e3 + e4);
    out[0] = e0 * inv; out[1] = e1 * inv; out[2] = e2 * inv;
    out[3] = e3 * inv; out[4] = e4 * inv;
}
__device__ __forceinline__ void rqs_one(const float* P, float xa, float& yo, float& ldo) {
    float W[5], t1[5], t2[5];
    #pragma unroll
    for (int p = 0; p < 5; ++p) W[p] = P[p];
    softmax5(W, t1);
    #pragma unroll
    for (int p = 0; p < 5; ++p) t1[p] *= 6.f;
    softmax5(t1, t2);
    float cw[6], wd[5];
    cw[0] = -3.f;
    float cs = 0.f;
    #pragma unroll
    for (int p = 0; p < 5; ++p) { float wv = 1.0e-3f + 0.995f * t2[p]; cs += wv; cw[p + 1] = 6.f * cs - 3.f; }
    cw[5] = 3.f;
    #pragma unroll
    for (int p = 0; p < 5; ++p) wd[p] = cw[p + 1] - cw[p];
    #pragma unroll
    for (int p = 0; p < 5; ++p) W[p] = P[5 + p];
    softmax5(W, t1);
    #pragma unroll
    for (int p = 0; p < 5; ++p) t1[p] *= 6.f;
    softmax5(t1, t2);
    float ch[6], hg[5];
    ch[0] = -3.f;
    cs = 0.f;
    #pragma unroll
    for (int p = 0; p < 5; ++p) { float hv = 1.0e-3f + 0.995f * t2[p]; cs += hv; ch[p + 1] = 6.f * cs - 3.f; }
    ch[5] = 3.f;
    #pragma unroll
    for (int p = 0; p < 5; ++p) hg[p] = ch[p + 1] - ch[p];
    float dv[6];
    const float padc = logf(expf(0.999f) - 1.f);
    float dve = 1.0e-3f + sp_f(padc);
    dv[0] = dve; dv[5] = dve;
    #pragma unroll
    for (int p = 0; p < 4; ++p) dv[p + 1] = 1.0e-3f + sp_f(sp_f(P[10 + p]));
    bool inside = (xa >= -3.f) && (xa <= 3.f);
    float xc = fminf(fmaxf(xa, -3.f), 3.f);
    float in_cw = cw[0], in_w = wd[0], in_ch = ch[0], in_h = hg[0], dk = dv[0], dk1 = dv[1];
    #pragma unroll
    for (int jb = 1; jb < 5; ++jb) {
        bool take = (xc >= cw[jb]);
        in_cw = take ? cw[jb] : in_cw;
        in_w  = take ? wd[jb] : in_w;
        in_ch = take ? ch[jb] : in_ch;
        in_h  = take ? hg[jb] : in_h;
        dk    = take ? dv[jb] : dk;
        dk1   = take ? dv[jb + 1] : dk1;
    }
    float th = (xc - in_cw) / in_w;
    float om = 1.f - th;
    float t1m = th * om;
    float delta = in_h / in_w;
    float num = in_h * (delta * th * th + dk * t1m);
    float den = delta + (dk + dk1 - 2.f * delta) * t1m;
    float y = in_ch + num / den;
    float dnum = delta * delta * (dk1 * th * th + 2.f * delta * t1m + dk * om * om);
    float ld = logf(dnum) - 2.f * logf(den);
    yo  = inside ? y : xa;
    ldo = inside ? ld : 0.f;
}

// ---------- prep: weights -> bf16 fragment order ----------
// w1f[stage][d 128][c2 16][lane 64] = ushort8: e -> w1[k=32*c2+8*(l>>4)+e][d*14+(l&15)] (0 if p>=14)
// w0f[stage][ct 32][c 4][lane 64]   = ushort8: e -> w0[k=32*c +8*(l>>4)+e][ct*16+(l&15)]
// b1p[stage][d 128][16]             = b1[d*14+p] (0 if p>=14)
__global__ void prep(const float* __restrict__ w1a, const float* __restrict__ w1b,
                     const float* __restrict__ w0a, const float* __restrict__ w0b,
                     const float* __restrict__ b1a, const float* __restrict__ b1b,
                     short* __restrict__ w1f, short* __restrict__ w0f, float* __restrict__ b1p) {
    int idx = blockIdx.x * 256 + threadIdx.x;
    if (idx < 262144) {
        int stage = idx >> 17, rem = idx & 131071;
        int d = rem >> 10, c2 = (rem >> 6) & 15, l = rem & 63;
        const float* src = stage ? w1b : w1a;
        int p = l & 15, g = l >> 4;
        short8 o;
        #pragma unroll
        for (int e = 0; e < 8; ++e) {
            int k = 32 * c2 + 8 * g + e;
            float v = (p < 14) ? src[(size_t)k * 1792 + d * 14 + p] : 0.f;
            o[e] = (short)f2bf(v);
        }
        *reinterpret_cast<short8*>(w1f + (size_t)stage * 1048576 + (size_t)rem * 8) = o;
    } else if (idx < 278528) {
        int r = idx - 262144;
        int stage = r >> 13, rem = r & 8191;
        int l = rem & 63;
        const float* src = stage ? w0b : w0a;
        int p = l & 15, g = l >> 4;
        int ct = rem >> 8, c = (rem >> 6) & 3;
        short8 o;
        #pragma unroll
        for (int e = 0; e < 8; ++e) {
            int k = 32 * c + 8 * g + e;
            o[e] = (short)f2bf(src[k * 512 + ct * 16 + p]);
        }
        *reinterpret_cast<short8*>(w0f + stage * 65536 + rem * 8) = o;
    } else if (idx < 282624) {
        int r = idx - 278528;
        int stage = r >> 11, rem = r & 2047;
        int d = rem >> 4, p = rem & 15;
        const float* src = stage ? b1b : b1a;
        b1p[stage * 2048 + rem] = (p < 14) ? src[d * 14 + p] : 0.f;
    }
}

// ---------- fused stage kernel ----------
template <int STAGE>
__global__ __launch_bounds__(256, 2)
void nsf_stage(const float* __restrict__ xin, float* __restrict__ zout,
               float* __restrict__ ld_out,
               const short* __restrict__ w0f, const float* __restrict__ b0,
               const short* __restrict__ w1f, const float* __restrict__ b1p) {
    __shared__ __align__(16) short hA2[32768];   // 64 KB: [rt2 4][c2 16][lane 64][e 8] bf16
    __shared__ __align__(16) float pbuf[4096];   // 16 KB: per-wave 1024 f32; aliased as A1 in phase 0
    short* A1 = reinterpret_cast<short*>(pbuf);  // 16 frags x 64 lanes x 8 bf16 = 16 KB

    const int tid = threadIdx.x;
    const int lane = tid & 63;
    const int w = tid >> 6;
    const int n0 = blockIdx.x * BM;

    const float* cond = STAGE ? zout : xin;
    const int coff = STAGE ? HALF : 0;
    const int aoff = STAGE ? 0 : HALF;     // activation half read from xin
    const int yoff = STAGE ? 0 : HALF;     // output half written to zout

    // ---- phase 0: cond tile -> bf16 A1 fragments in LDS
    #pragma unroll
    for (int t = 0; t < 4; ++t) {
        int idx = t * 256 + tid;             // (rt*4+c)*64 + l
        int fr = idx >> 6, l = idx & 63;
        int rt = fr >> 2, c = fr & 3;
        int row = rt * 16 + (l & 15);
        int kb = 32 * c + 8 * (l >> 4);
        const float* sp = cond + (size_t)(n0 + row) * DIMX + coff + kb;
        short8 o;
        #pragma unroll
        for (int e = 0; e < 8; ++e) o[e] = (short)f2bf(sp[e]);
        *reinterpret_cast<short8*>(A1 + idx * 8) = o;
    }
    __syncthreads();

    // ---- phase 1: h = tanh(cond @ w0 + b0) -> bf16 A2-frag order in LDS
    for (int rt = 0; rt < 4; ++rt) {
        short8 a1[4];
        #pragma unroll
        for (int c = 0; c < 4; ++c)
            a1[c] = *reinterpret_cast<const short8*>(A1 + ((rt * 4 + c) * 64 + lane) * 8);
        #pragma unroll
        for (int j = 0; j < 8; ++j) {
            int ct = w * 8 + j;
            f32x4 acc = {0.f, 0.f, 0.f, 0.f};
            #pragma unroll
            for (int c = 0; c < 4; ++c) {
                short8 b = *reinterpret_cast<const short8*>(w0f + ((ct * 4 + c) * 64 + lane) * 8);
                acc = __builtin_amdgcn_mfma_f32_16x16x32_bf16(a1[c], b, acc, 0, 0, 0);
            }
            float bv = b0[ct * 16 + (lane & 15)];
            int q = (2 * ct + ((lane & 15) >> 3)) & 3;
            int c2 = ct >> 1;
            #pragma unroll
            for (int r = 0; r < 4; ++r) {
                float hv = tanhf(acc[r] + bv);
                int i = (lane >> 4) * 4 + r;
                hA2[((rt * 16 + c2) * 64 + (i + 16 * q)) * 8 + (lane & 7)] = (short)f2bf(hv);
            }
        }
    }
    __syncthreads();

    // ---- phase 2: params = h @ w1 + b1 (MFMA), transpose, spline
    float ldp[4] = {0.f, 0.f, 0.f, 0.f};
    float* pb = pbuf + w * 1024;             // wave-private transpose buffer
    for (int rt2 = 0; rt2 < 4; ++rt2) {
        short8 a2[16];
        #pragma unroll
        for (int c2 = 0; c2 < 16; ++c2)
            a2[c2] = *reinterpret_cast<const short8*>(hA2 + ((rt2 * 16 + c2) * 64 + lane) * 8);
        for (int dg = 0; dg < 8; ++dg) {
            const int d0 = w * 32 + dg * 4;
            f32x4 acc[4];
            #pragma unroll
            for (int dd = 0; dd < 4; ++dd) acc[dd] = (f32x4){0.f, 0.f, 0.f, 0.f};
            #pragma unroll
            for (int c2 = 0; c2 < 16; ++c2) {
                #pragma unroll
                for (int dd = 0; dd < 4; ++dd) {
                    short8 b = *reinterpret_cast<const short8*>(
                        w1f + ((size_t)((d0 + dd) * 16 + c2) * 64 + lane) * 8);
                    acc[dd] = __builtin_amdgcn_mfma_f32_16x16x32_bf16(a2[c2], b, acc[dd], 0, 0, 0);
                }
            }
            // bias + XOR-swizzled transpose through wave-private LDS
            #pragma unroll
            for (int dd = 0; dd < 4; ++dd) {
                float bv = b1p[(d0 + dd) * 16 + (lane & 15)];
                #pragma unroll
                for (int r = 0; r < 4; ++r) {
                    int rl = (lane >> 4) * 4 + r;
                    pb[dd * 256 + rl * 16 + ((lane & 15) ^ (((rl >> 1) & 3) << 2))] = acc[dd][r] + bv;
                }
            }
            asm volatile("s_waitcnt lgkmcnt(0)" ::: "memory");
            __builtin_amdgcn_sched_barrier(0);
            // spline: lane -> (row = lane&15, d = d0 + lane>>4)
            {
                int rl = lane & 15, dd = lane >> 4;
                int s = ((rl >> 1) & 3) << 2;
                const float* rb = pb + dd * 256 + rl * 16;
                float P[16];
                #pragma unroll
                for (int qd = 0; qd < 4; ++qd) {
                    f32x4 v = *reinterpret_cast<const f32x4*>(rb + ((qd * 4) ^ s));
                    P[qd * 4 + 0] = v[0]; P[qd * 4 + 1] = v[1];
                    P[qd * 4 + 2] = v[2]; P[qd * 4 + 3] = v[3];
                }
                size_t nrow = (size_t)(n0 + rt2 * 16 + rl) * DIMX;
                float xa = xin[nrow + aoff + d0 + dd];
                float y, ldv;
                rqs_one(P, xa, y, ldv);
                zout[nrow + yoff + d0 + dd] = y;
                ldv += __shfl_xor(ldv, 16, 64);
                ldv += __shfl_xor(ldv, 32, 64);
                ldp[rt2] += ldv;      // lanes 0..15 carry the canonical row sums
            }
        }
    }

    // ---- log-det: per-wave partials -> LDS -> block reduce
    if (lane < 16) {
        #pragma unroll
        for (int rt2 = 0; rt2 < 4; ++rt2) pb[rt2 * 16 + lane] = ldp[rt2];
    }
    __syncthreads();
    if (tid < BM) {
        float s = pbuf[tid] + pbuf[1024 + tid] + pbuf[2048 + tid] + pbuf[3072 + tid];
        if (STAGE == 0) ld_out[n0 + tid] = s;
        else            ld_out[n0 + tid] += s;
    }
}

// ---------- launch ----------
extern "C" void kernel_launch(void* const* d_in, const int* in_sizes, int n_in,
                              void* d_out, int out_size, void* d_ws, size_t ws_size,
                              hipStream_t stream) {
    const float* x     = (const float*)d_in[0];
    const float* f0_w0 = (const float*)d_in[1];
    const float* f0_b0 = (const float*)d_in[2];
    const float* f0_w1 = (const float*)d_in[3];
    const float* f0_b1 = (const float*)d_in[4];
    const float* f1_w0 = (const float*)d_in[5];
    const float* f1_b0 = (const float*)d_in[6];
    const float* f1_w1 = (const float*)d_in[7];
    const float* f1_b1 = (const float*)d_in[8];

    float* zout = (float*)d_out;
    float* ld   = zout + (size_t)NROWS * DIMX;

    short* w1f = (short*)d_ws;                                     // 2 x 2 MB
    short* w0f = (short*)((char*)d_ws + 4 * 1024 * 1024);          // 2 x 128 KB
    float* b1p = (float*)((char*)d_ws + 4 * 1024 * 1024 + 256 * 1024); // 2 x 8 KB

    prep<<<1104, 256, 0, stream>>>(f0_w1, f1_w1, f0_w0, f1_w0, f0_b1, f1_b1, w1f, w0f, b1p);
    nsf_stage<0><<<NROWS / BM, 256, 0, stream>>>(x, zout, ld, w0f, f0_b0, w1f, b1p);
    nsf_stage<1><<<NROWS / BM, 256, 0, stream>>>(x, zout, ld, w0f + 65536, f1_b0,
                                                 w1f + 1048576, b1p + 2048);
}

// Round 3
// 399.649 us; speedup vs baseline: 9.7687x; 1.6393x over previous
//
#include <hip/hip_runtime.h>
#include <math.h>

// NSF_CL coupling flow via bf16 MFMA. N=32768, dim=256 (half=128), hid=512, K=5.
// Round 3: fast transcendentals (v_exp/v_log/v_rcp) + 2-rt2-in-flight GEMM2
// (halves w1f L2 re-reads). Structure otherwise identical to round 2 (validated).

#define NROWS 32768
#define DIMX  256
#define HALF  128
#define HID   512
#define BM    64     // rows per block

typedef __attribute__((ext_vector_type(8))) short short8;   // 8 bf16 = 4 VGPR
typedef __attribute__((ext_vector_type(4))) float f32x4;

__device__ __forceinline__ unsigned short f2bf(float x) {   // RNE f32->bf16 bits
    unsigned int u = __float_as_uint(x);
    u += 0x7fffu + ((u >> 16) & 1u);
    return (unsigned short)(u >> 16);
}

__device__ __forceinline__ float frcp(float x) { return __builtin_amdgcn_rcpf(x); }

// softplus: max(x,0) + log1p(exp(-|x|)), fast form
__device__ __forceinline__ float spf(float x) {
    return fmaxf(x, 0.f) + __logf(1.f + __expf(-fabsf(x)));
}

// out = 1e-3 + 0.995 * softmax(6 * softmax(P))   (double softmax, fused scales)
__device__ __forceinline__ void dsm5(const float* P, float* out) {
    float e[5];
    float m = fmaxf(fmaxf(fmaxf(P[0], P[1]), fmaxf(P[2], P[3])), P[4]);
    float s = 0.f;
    #pragma unroll
    for (int p = 0; p < 5; ++p) { e[p] = __expf(P[p] - m); s += e[p]; }
    float r = 6.f * frcp(s);
    float s2 = 0.f;
    // second softmax: args in [0,6] -> no max subtraction needed (exp<=403)
    #pragma unroll
    for (int p = 0; p < 5; ++p) { e[p] = __expf(e[p] * r); s2 += e[p]; }
    float r2 = 0.995f * frcp(s2);
    #pragma unroll
    for (int p = 0; p < 5; ++p) out[p] = 1.0e-3f + e[p] * r2;
}

// P[0..4]=W raw, P[5..9]=H raw, P[10..13]=D raw. Fused cumsum + bucket select.
__device__ __forceinline__ void rqs_fast(const float* P, float xa, float& yo, float& ldo) {
    float wv[5], hv[5];
    dsm5(P, wv);
    dsm5(P + 5, hv);
    float dvi[4];
    #pragma unroll
    for (int p = 0; p < 4; ++p) dvi[p] = 1.0e-3f + spf(spf(P[10 + p]));
    // pad-end derivs: MIN_D + softplus(log(exp(1-MIN_D)-1)) == 1.0 exactly
    float xc = fminf(fmaxf(xa, -3.f), 3.f);
    float csw = wv[0], csh = hv[0];
    float in_cw = -3.f, in_ch = -3.f;
    float in_w = 6.f * csw, in_h = 6.f * csh;   // cw[1]-cw[0], ch[1]-ch[0]
    float dk = 1.f, dk1 = dvi[0];               // bucket 0: dv[0]=1, dv[1]=dvi[0]
    #pragma unroll
    for (int p = 1; p < 5; ++p) {
        float cwp = 6.f * csw - 3.f;            // cw[p]
        float chp = 6.f * csh - 3.f;            // ch[p]
        csw += wv[p]; csh += hv[p];
        float cwp1 = (p == 4) ? 3.f : (6.f * csw - 3.f);
        float chp1 = (p == 4) ? 3.f : (6.f * csh - 3.f);
        bool take = (xc >= cwp);
        in_cw = take ? cwp : in_cw;
        in_w  = take ? (cwp1 - cwp) : in_w;
        in_ch = take ? chp : in_ch;
        in_h  = take ? (chp1 - chp) : in_h;
        dk    = take ? dvi[p - 1] : dk;
        dk1   = take ? ((p == 4) ? 1.f : dvi[p]) : dk1;
    }
    float rw = frcp(in_w);
    float th = (xc - in_cw) * rw;
    float om = 1.f - th;
    float t1m = th * om;
    float delta = in_h * rw;
    float num = in_h * (delta * th * th + dk * t1m);
    float den = delta + (dk + dk1 - 2.f * delta) * t1m;
    float y = in_ch + num * frcp(den);
    float dnum = delta * delta * (dk1 * th * th + 2.f * delta * t1m + dk * om * om);
    float ld = __logf(dnum) - 2.f * __logf(den);
    bool inside = (xa >= -3.f) && (xa <= 3.f);
    yo  = inside ? y : xa;
    ldo = inside ? ld : 0.f;
}

// ---------- prep: weights -> bf16 fragment order (unchanged from r2) ----------
// w1f[stage][d 128][c2 16][lane 64] = ushort8: e -> w1[k=32*c2+8*(l>>4)+e][d*14+(l&15)] (0 if p>=14)
// w0f[stage][ct 32][c 4][lane 64]   = ushort8: e -> w0[k=32*c +8*(l>>4)+e][ct*16+(l&15)]
// b1p[stage][d 128][16]             = b1[d*14+p] (0 if p>=14)
__global__ void prep(const float* __restrict__ w1a, const float* __restrict__ w1b,
                     const float* __restrict__ w0a, const float* __restrict__ w0b,
                     const float* __restrict__ b1a, const float* __restrict__ b1b,
                     short* __restrict__ w1f, short* __restrict__ w0f, float* __restrict__ b1p) {
    int idx = blockIdx.x * 256 + threadIdx.x;
    if (idx < 262144) {
        int stage = idx >> 17, rem = idx & 131071;
        int d = rem >> 10, c2 = (rem >> 6) & 15, l = rem & 63;
        const float* src = stage ? w1b : w1a;
        int p = l & 15, g = l >> 4;
        short8 o;
        #pragma unroll
        for (int e = 0; e < 8; ++e) {
            int k = 32 * c2 + 8 * g + e;
            float v = (p < 14) ? src[(size_t)k * 1792 + d * 14 + p] : 0.f;
            o[e] = (short)f2bf(v);
        }
        *reinterpret_cast<short8*>(w1f + (size_t)stage * 1048576 + (size_t)rem * 8) = o;
    } else if (idx < 278528) {
        int r = idx - 262144;
        int stage = r >> 13, rem = r & 8191;
        int l = rem & 63;
        const float* src = stage ? w0b : w0a;
        int p = l & 15, g = l >> 4;
        int ct = rem >> 8, c = (rem >> 6) & 3;
        short8 o;
        #pragma unroll
        for (int e = 0; e < 8; ++e) {
            int k = 32 * c + 8 * g + e;
            o[e] = (short)f2bf(src[k * 512 + ct * 16 + p]);
        }
        *reinterpret_cast<short8*>(w0f + stage * 65536 + rem * 8) = o;
    } else if (idx < 282624) {
        int r = idx - 278528;
        int stage = r >> 11, rem = r & 2047;
        int d = rem >> 4, p = rem & 15;
        const float* src = stage ? b1b : b1a;
        b1p[stage * 2048 + rem] = (p < 14) ? src[d * 14 + p] : 0.f;
    }
}

// ---------- fused stage kernel ----------
template <int STAGE>
__global__ __launch_bounds__(256, 2)
void nsf_stage(const float* __restrict__ xin, float* __restrict__ zout,
               float* __restrict__ ld_out,
               const short* __restrict__ w0f, const float* __restrict__ b0,
               const short* __restrict__ w1f, const float* __restrict__ b1p) {
    __shared__ __align__(16) short hA2[32768];   // 64 KB: [rt2 4][c2 16][lane 64][e 8] bf16
    __shared__ __align__(16) float pbuf[4096];   // 16 KB: per-wave 1024 f32; aliased as A1 in phase 0
    short* A1 = reinterpret_cast<short*>(pbuf);  // 16 frags x 64 lanes x 8 bf16 = 16 KB

    const int tid = threadIdx.x;
    const int lane = tid & 63;
    const int w = tid >> 6;
    const int n0 = blockIdx.x * BM;

    const float* cond = STAGE ? zout : xin;
    const int coff = STAGE ? HALF : 0;
    const int aoff = STAGE ? 0 : HALF;     // activation half read from xin
    const int yoff = STAGE ? 0 : HALF;     // output half written to zout

    // ---- phase 0: cond tile -> bf16 A1 fragments in LDS
    #pragma unroll
    for (int t = 0; t < 4; ++t) {
        int idx = t * 256 + tid;             // (rt*4+c)*64 + l
        int fr = idx >> 6, l = idx & 63;
        int rt = fr >> 2, c = fr & 3;
        int row = rt * 16 + (l & 15);
        int kb = 32 * c + 8 * (l >> 4);
        const float* sp = cond + (size_t)(n0 + row) * DIMX + coff + kb;
        short8 o;
        #pragma unroll
        for (int e = 0; e < 8; ++e) o[e] = (short)f2bf(sp[e]);
        *reinterpret_cast<short8*>(A1 + idx * 8) = o;
    }
    __syncthreads();

    // ---- phase 1: h = tanh(cond @ w0 + b0) -> bf16 A2-frag order in LDS
    for (int rt = 0; rt < 4; ++rt) {
        short8 a1[4];
        #pragma unroll
        for (int c = 0; c < 4; ++c)
            a1[c] = *reinterpret_cast<const short8*>(A1 + ((rt * 4 + c) * 64 + lane) * 8);
        #pragma unroll
        for (int j = 0; j < 8; ++j) {
            int ct = w * 8 + j;
            f32x4 acc = {0.f, 0.f, 0.f, 0.f};
            #pragma unroll
            for (int c = 0; c < 4; ++c) {
                short8 b = *reinterpret_cast<const short8*>(w0f + ((ct * 4 + c) * 64 + lane) * 8);
                acc = __builtin_amdgcn_mfma_f32_16x16x32_bf16(a1[c], b, acc, 0, 0, 0);
            }
            float bv = b0[ct * 16 + (lane & 15)];
            int q = (2 * ct + ((lane & 15) >> 3)) & 3;
            int c2 = ct >> 1;
            #pragma unroll
            for (int r = 0; r < 4; ++r) {
                float av = acc[r] + bv;
                float e2 = __expf(2.f * av);                 // fast tanh
                float hvf = 1.f - 2.f * frcp(e2 + 1.f);
                int i = (lane >> 4) * 4 + r;
                hA2[((rt * 16 + c2) * 64 + (i + 16 * q)) * 8 + (lane & 7)] = (short)f2bf(hvf);
            }
        }
    }
    __syncthreads();

    // ---- phase 2: params = h @ w1 + b1 (MFMA, 2 rt2 in flight), transpose, spline
    float ldp[4] = {0.f, 0.f, 0.f, 0.f};
    float* pb = pbuf + w * 1024;             // wave-private transpose buffer
    for (int pr = 0; pr < 2; ++pr) {         // row pair: rt2 = pr*2 + q
        short8 a2[2][16];
        #pragma unroll
        for (int q = 0; q < 2; ++q)
            #pragma unroll
            for (int c2 = 0; c2 < 16; ++c2)
                a2[q][c2] = *reinterpret_cast<const short8*>(
                    hA2 + (((pr * 2 + q) * 16 + c2) * 64 + lane) * 8);
        for (int dg = 0; dg < 8; ++dg) {
            const int d0 = w * 32 + dg * 4;
            f32x4 acc[2][4];
            #pragma unroll
            for (int q = 0; q < 2; ++q)
                #pragma unroll
                for (int dd = 0; dd < 4; ++dd) acc[q][dd] = (f32x4){0.f, 0.f, 0.f, 0.f};
            #pragma unroll
            for (int c2 = 0; c2 < 16; ++c2) {
                #pragma unroll
                for (int dd = 0; dd < 4; ++dd) {
                    short8 b = *reinterpret_cast<const short8*>(
                        w1f + ((size_t)((d0 + dd) * 16 + c2) * 64 + lane) * 8);
                    acc[0][dd] = __builtin_amdgcn_mfma_f32_16x16x32_bf16(a2[0][c2], b, acc[0][dd], 0, 0, 0);
                    acc[1][dd] = __builtin_amdgcn_mfma_f32_16x16x32_bf16(a2[1][c2], b, acc[1][dd], 0, 0, 0);
                }
            }
            float bvv[4];
            #pragma unroll
            for (int dd = 0; dd < 4; ++dd) bvv[dd] = b1p[(d0 + dd) * 16 + (lane & 15)];
            #pragma unroll
            for (int q = 0; q < 2; ++q) {
                const int rt2 = pr * 2 + q;
                // bias + XOR-swizzled transpose through wave-private LDS
                #pragma unroll
                for (int dd = 0; dd < 4; ++dd) {
                    #pragma unroll
                    for (int r = 0; r < 4; ++r) {
                        int rl = (lane >> 4) * 4 + r;
                        pb[dd * 256 + rl * 16 + ((lane & 15) ^ (((rl >> 1) & 3) << 2))] =
                            acc[q][dd][r] + bvv[dd];
                    }
                }
                asm volatile("s_waitcnt lgkmcnt(0)" ::: "memory");
                __builtin_amdgcn_sched_barrier(0);
                // spline: lane -> (row = lane&15, d = d0 + lane>>4)
                {
                    int rl = lane & 15, dd = lane >> 4;
                    int s = ((rl >> 1) & 3) << 2;
                    const float* rb = pb + dd * 256 + rl * 16;
                    float P[16];
                    #pragma unroll
                    for (int qd = 0; qd < 4; ++qd) {
                        f32x4 v = *reinterpret_cast<const f32x4*>(rb + ((qd * 4) ^ s));
                        P[qd * 4 + 0] = v[0]; P[qd * 4 + 1] = v[1];
                        P[qd * 4 + 2] = v[2]; P[qd * 4 + 3] = v[3];
                    }
                    size_t nrow = (size_t)(n0 + rt2 * 16 + rl) * DIMX;
                    float xa = xin[nrow + aoff + d0 + dd];
                    float y, ldv;
                    rqs_fast(P, xa, y, ldv);
                    zout[nrow + yoff + d0 + dd] = y;
                    ldv += __shfl_xor(ldv, 16, 64);
                    ldv += __shfl_xor(ldv, 32, 64);
                    ldp[rt2] += ldv;      // lanes 0..15 carry the canonical row sums
                }
            }
        }
    }

    // ---- log-det: per-wave partials -> LDS -> block reduce
    if (lane < 16) {
        #pragma unroll
        for (int rt2 = 0; rt2 < 4; ++rt2) pb[rt2 * 16 + lane] = ldp[rt2];
    }
    __syncthreads();
    if (tid < BM) {
        float s = pbuf[tid] + pbuf[1024 + tid] + pbuf[2048 + tid] + pbuf[3072 + tid];
        if (STAGE == 0) ld_out[n0 + tid] = s;
        else            ld_out[n0 + tid] += s;
    }
}

// ---------- launch ----------
extern "C" void kernel_launch(void* const* d_in, const int* in_sizes, int n_in,
                              void* d_out, int out_size, void* d_ws, size_t ws_size,
                              hipStream_t stream) {
    const float* x     = (const float*)d_in[0];
    const float* f0_w0 = (const float*)d_in[1];
    const float* f0_b0 = (const float*)d_in[2];
    const float* f0_w1 = (const float*)d_in[3];
    const float* f0_b1 = (const float*)d_in[4];
    const float* f1_w0 = (const float*)d_in[5];
    const float* f1_b0 = (const float*)d_in[6];
    const float* f1_w1 = (const float*)d_in[7];
    const float* f1_b1 = (const float*)d_in[8];

    float* zout = (float*)d_out;
    float* ld   = zout + (size_t)NROWS * DIMX;

    short* w1f = (short*)d_ws;                                     // 2 x 2 MB
    short* w0f = (short*)((char*)d_ws + 4 * 1024 * 1024);          // 2 x 128 KB
    float* b1p = (float*)((char*)d_ws + 4 * 1024 * 1024 + 256 * 1024); // 2 x 8 KB

    prep<<<1104, 256, 0, stream>>>(f0_w1, f1_w1, f0_w0, f1_w0, f0_b1, f1_b1, w1f, w0f, b1p);
    nsf_stage<0><<<NROWS / BM, 256, 0, stream>>>(x, zout, ld, w0f, f0_b0, w1f, b1p);
    nsf_stage<1><<<NROWS / BM, 256, 0, stream>>>(x, zout, ld, w0f + 65536, f1_b0,
                                                 w1f + 1048576, b1p + 2048);
}